// Round 1
// baseline (3325.299 us; speedup 1.0000x reference)
//
#include <hip/hip_runtime.h>
#include <cstddef>

#define N_NODES 100000
#define N_EDGES 1600000

// ---------------- layer 1: scatter x[src] into agg1[dst], Fin=4 ----------------
__global__ __launch_bounds__(256) void k_scatter4(
    const float* __restrict__ x, const int* __restrict__ src,
    const int* __restrict__ dst, float* __restrict__ agg1) {
  int tid = blockIdx.x * 256 + threadIdx.x;
  int e = tid >> 2;
  if (e >= N_EDGES) return;
  int f = tid & 3;
  atomicAdd(agg1 + dst[e] * 4 + f, x[src[e] * 4 + f]);
}

// ---------------- layer 1 dense: h1 = relu(agg1@W1_rel.T + b1 + x@W1_root.T) ----
__global__ __launch_bounds__(256) void k_layer1(
    const float* __restrict__ x, const float* __restrict__ agg1,
    const float* __restrict__ W1_rel, const float* __restrict__ b1,
    const float* __restrict__ W1_root, float* __restrict__ h1) {
  int tid = blockIdx.x * 256 + threadIdx.x;
  if (tid >= N_NODES * 128) return;
  int node = tid >> 7;
  int f = tid & 127;
  float4 a  = *(const float4*)(agg1 + node * 4);
  float4 xv = *(const float4*)(x + node * 4);
  float4 wr = *(const float4*)(W1_rel + f * 4);
  float4 wo = *(const float4*)(W1_root + f * 4);
  float v = b1[f]
      + a.x  * wr.x + a.y  * wr.y + a.z  * wr.z + a.w  * wr.w
      + xv.x * wo.x + xv.y * wo.y + xv.z * wo.z + xv.w * wo.w;
  h1[tid] = fmaxf(v, 0.0f);  // tid == node*128 + f
}

// ---------------- layer 2: scatter h1[src] into agg2[dst], F=128 ----------------
__global__ __launch_bounds__(256) void k_scatter128(
    const float* __restrict__ h1, const int* __restrict__ src,
    const int* __restrict__ dst, float* __restrict__ agg2) {
  int tid = blockIdx.x * 256 + threadIdx.x;
  int e = tid >> 5;             // 32 threads per edge
  if (e >= N_EDGES) return;
  int f4 = (tid & 31) << 2;     // 4 features per thread
  int s = src[e], d = dst[e];
  float4 v = *(const float4*)(h1 + (size_t)s * 128 + f4);
  float* p = agg2 + (size_t)d * 128 + f4;
  atomicAdd(p + 0, v.x);
  atomicAdd(p + 1, v.y);
  atomicAdd(p + 2, v.z);
  atomicAdd(p + 3, v.w);
}

// -------- layer 2 dense + mean-pool partial: gsum[f] += relu(...) over nodes ----
// grid = (128, 4): blockIdx.y selects a 32-wide output-feature slice.
// LDS holds the [256 x 32] transposed weight slice (W2_rel || W2_root stacked on k).
__global__ __launch_bounds__(256) void k_layer2pool(
    const float* __restrict__ h1, const float* __restrict__ agg2,
    const float* __restrict__ W2_rel, const float* __restrict__ b2,
    const float* __restrict__ W2_root, float* __restrict__ gsum) {
  __shared__ float lds_w[256 * 32];   // [k][f_local], 32 KB
  int tid = threadIdx.x;
  int f0 = blockIdx.y * 32;

  {  // stage weights transposed: lds_w[k][fl] = Wcat[f0+fl][k]
    int fl = tid >> 3;   // 0..31
    int q  = tid & 7;    // k-chunk of 32
    int fg = f0 + fl;
    const float* wsrc = (q < 4) ? (W2_rel + fg * 128 + q * 32)
                                : (W2_root + fg * 128 + (q - 4) * 32);
    int kbase = q * 32;
#pragma unroll
    for (int j = 0; j < 32; j += 4) {
      float4 w = *(const float4*)(wsrc + j);
      lds_w[(kbase + j + 0) * 32 + fl] = w.x;
      lds_w[(kbase + j + 1) * 32 + fl] = w.y;
      lds_w[(kbase + j + 2) * 32 + fl] = w.z;
      lds_w[(kbase + j + 3) * 32 + fl] = w.w;
    }
  }
  __syncthreads();

  int f = tid & 31;
  int g = tid >> 5;   // 0..7 node sub-group
  float bias = b2[f0 + f];

  int npb = (N_NODES + gridDim.x - 1) / gridDim.x;
  int nstart = blockIdx.x * npb;
  int nend = min(nstart + npb, N_NODES);

  float fsum = 0.0f;
  for (int base = nstart + g * 4; base < nend; base += 32) {
    int m0 = base;
    int m1 = min(base + 1, N_NODES - 1);
    int m2 = min(base + 2, N_NODES - 1);
    int m3 = min(base + 3, N_NODES - 1);
    float acc0 = bias, acc1 = bias, acc2 = bias, acc3 = bias;

    const float* A0 = agg2 + (size_t)m0 * 128;
    const float* A1 = agg2 + (size_t)m1 * 128;
    const float* A2 = agg2 + (size_t)m2 * 128;
    const float* A3 = agg2 + (size_t)m3 * 128;
#pragma unroll 8
    for (int k = 0; k < 128; k += 4) {
      float4 x0 = *(const float4*)(A0 + k);
      float4 x1 = *(const float4*)(A1 + k);
      float4 x2 = *(const float4*)(A2 + k);
      float4 x3 = *(const float4*)(A3 + k);
      float w0 = lds_w[(k + 0) * 32 + f];
      float w1 = lds_w[(k + 1) * 32 + f];
      float w2 = lds_w[(k + 2) * 32 + f];
      float w3 = lds_w[(k + 3) * 32 + f];
      acc0 += x0.x * w0 + x0.y * w1 + x0.z * w2 + x0.w * w3;
      acc1 += x1.x * w0 + x1.y * w1 + x1.z * w2 + x1.w * w3;
      acc2 += x2.x * w0 + x2.y * w1 + x2.z * w2 + x2.w * w3;
      acc3 += x3.x * w0 + x3.y * w1 + x3.z * w2 + x3.w * w3;
    }
    const float* H0 = h1 + (size_t)m0 * 128;
    const float* H1 = h1 + (size_t)m1 * 128;
    const float* H2 = h1 + (size_t)m2 * 128;
    const float* H3 = h1 + (size_t)m3 * 128;
#pragma unroll 8
    for (int k = 0; k < 128; k += 4) {
      float4 x0 = *(const float4*)(H0 + k);
      float4 x1 = *(const float4*)(H1 + k);
      float4 x2 = *(const float4*)(H2 + k);
      float4 x3 = *(const float4*)(H3 + k);
      float w0 = lds_w[(128 + k + 0) * 32 + f];
      float w1 = lds_w[(128 + k + 1) * 32 + f];
      float w2 = lds_w[(128 + k + 2) * 32 + f];
      float w3 = lds_w[(128 + k + 3) * 32 + f];
      acc0 += x0.x * w0 + x0.y * w1 + x0.z * w2 + x0.w * w3;
      acc1 += x1.x * w0 + x1.y * w1 + x1.z * w2 + x1.w * w3;
      acc2 += x2.x * w0 + x2.y * w1 + x2.z * w2 + x2.w * w3;
      acc3 += x3.x * w0 + x3.y * w1 + x3.z * w2 + x3.w * w3;
    }
    fsum += (base + 0 < nend) ? fmaxf(acc0, 0.0f) : 0.0f;
    fsum += (base + 1 < nend) ? fmaxf(acc1, 0.0f) : 0.0f;
    fsum += (base + 2 < nend) ? fmaxf(acc2, 0.0f) : 0.0f;
    fsum += (base + 3 < nend) ? fmaxf(acc3, 0.0f) : 0.0f;
  }
  atomicAdd(gsum + f0 + f, fsum);
}

// ---------------- head: out = (gsum/N) @ Wlin.T + blin ----------------
__global__ void k_final(const float* __restrict__ gsum, const float* __restrict__ Wlin,
                        const float* __restrict__ blin, float* __restrict__ out) {
  int lane = threadIdx.x;  // 64 threads
  float g0 = gsum[lane];
  float g1 = gsum[lane + 64];
  float s0 = g0 * Wlin[lane]       + g1 * Wlin[lane + 64];
  float s1 = g0 * Wlin[128 + lane] + g1 * Wlin[192 + lane];
#pragma unroll
  for (int off = 32; off > 0; off >>= 1) {
    s0 += __shfl_down(s0, off);
    s1 += __shfl_down(s1, off);
  }
  if (lane == 0) {
    const float inv = 1.0f / (float)N_NODES;
    out[0] = s0 * inv + blin[0];
    out[1] = s1 * inv + blin[1];
  }
}

extern "C" void kernel_launch(void* const* d_in, const int* in_sizes, int n_in,
                              void* d_out, int out_size, void* d_ws, size_t ws_size,
                              hipStream_t stream) {
  const float* x       = (const float*)d_in[0];
  const int*   ei      = (const int*)d_in[1];
  const float* W1_rel  = (const float*)d_in[2];
  const float* b1      = (const float*)d_in[3];
  const float* W1_root = (const float*)d_in[4];
  const float* W2_rel  = (const float*)d_in[5];
  const float* b2      = (const float*)d_in[6];
  const float* W2_root = (const float*)d_in[7];
  const float* Wlin    = (const float*)d_in[8];
  const float* blin    = (const float*)d_in[9];
  const int* src = ei;            // edge_index[0]
  const int* dst = ei + N_EDGES;  // edge_index[1]
  float* out = (float*)d_out;

  // workspace layout (bytes): agg1 @0 (1.6MB) | h1 @2MB (51.2MB) | agg2 @54MB (51.2MB) | gsum @106MB
  char* ws = (char*)d_ws;
  float* agg1 = (float*)(ws);
  float* h1   = (float*)(ws + (size_t)(2)   * 1024 * 1024);
  float* agg2 = (float*)(ws + (size_t)(54)  * 1024 * 1024);
  float* gsum = (float*)(ws + (size_t)(106) * 1024 * 1024);

  hipMemsetAsync(agg1, 0, (size_t)N_NODES * 4 * sizeof(float), stream);
  hipMemsetAsync(agg2, 0, (size_t)N_NODES * 128 * sizeof(float), stream);
  hipMemsetAsync(gsum, 0, 128 * sizeof(float), stream);

  k_scatter4<<<(N_EDGES * 4 + 255) / 256, 256, 0, stream>>>(x, src, dst, agg1);
  k_layer1<<<(N_NODES * 128 + 255) / 256, 256, 0, stream>>>(x, agg1, W1_rel, b1, W1_root, h1);
  k_scatter128<<<(N_EDGES * 32 + 255) / 256, 256, 0, stream>>>(h1, src, dst, agg2);
  k_layer2pool<<<dim3(128, 4), 256, 0, stream>>>(h1, agg2, W2_rel, b2, W2_root, gsum);
  k_final<<<1, 64, 0, stream>>>(gsum, Wlin, blin, out);
}

// Round 2
// 855.418 us; speedup vs baseline: 3.8873x; 3.8873x over previous
//
#include <hip/hip_runtime.h>
#include <cstddef>

#define N_NODES 100000
#define N_EDGES 1600000

// ============ CSR build ============
// cursor doubles as histogram, then as fill cursor.
__global__ __launch_bounds__(256) void k_hist(const int* __restrict__ dst,
                                              int* __restrict__ cursor) {
  int e = blockIdx.x * 256 + threadIdx.x;
  if (e < N_EDGES) atomicAdd(&cursor[dst[e]], 1);
}

// Per-block scan of degrees; one global atomic per block allocates the segment
// base (segment order across blocks is arbitrary — sums are per-node, so fine).
__global__ __launch_bounds__(256) void k_alloc(int* __restrict__ cursor,
                                               int* __restrict__ row_start,
                                               int* __restrict__ gcursor) {
  __shared__ int s[256];
  __shared__ int base;
  int i = blockIdx.x * 256 + threadIdx.x;
  int t = threadIdx.x;
  int v = (i < N_NODES) ? cursor[i] : 0;
  s[t] = v;
  __syncthreads();
#pragma unroll
  for (int off = 1; off < 256; off <<= 1) {
    int tmp = (t >= off) ? s[t - off] : 0;
    __syncthreads();
    s[t] += tmp;
    __syncthreads();
  }
  if (t == 255) base = atomicAdd(gcursor, s[255]);
  __syncthreads();
  if (i < N_NODES) {
    int start = base + s[t] - v;  // exclusive scan
    row_start[i] = start;
    cursor[i] = start;
  }
}

__global__ __launch_bounds__(256) void k_fill(const int* __restrict__ src,
                                              const int* __restrict__ dst,
                                              int* __restrict__ cursor,
                                              int* __restrict__ csr_src) {
  int e = blockIdx.x * 256 + threadIdx.x;
  if (e >= N_EDGES) return;
  int pos = atomicAdd(&cursor[dst[e]], 1);
  csr_src[pos] = src[e];
}
// After k_fill: cursor[n] == segment end for node n.

// ============ layer 1: pull-aggregate x (Fin=4), thread per node ============
__global__ __launch_bounds__(256) void k_pull4(
    const float* __restrict__ x, const int* __restrict__ row_start,
    const int* __restrict__ row_end, const int* __restrict__ csr_src,
    float* __restrict__ agg1) {
  int n = blockIdx.x * 256 + threadIdx.x;
  if (n >= N_NODES) return;
  int rs = row_start[n], re = row_end[n];
  float4 acc = make_float4(0.f, 0.f, 0.f, 0.f);
  for (int i = rs; i < re; ++i) {
    int s = csr_src[i];
    float4 v = *(const float4*)(x + (size_t)s * 4);
    acc.x += v.x; acc.y += v.y; acc.z += v.z; acc.w += v.w;
  }
  *(float4*)(agg1 + (size_t)n * 4) = acc;
}

// ============ layer 1 dense: h1 = relu(agg1@W1_rel.T + b1 + x@W1_root.T) ====
__global__ __launch_bounds__(256) void k_layer1(
    const float* __restrict__ x, const float* __restrict__ agg1,
    const float* __restrict__ W1_rel, const float* __restrict__ b1,
    const float* __restrict__ W1_root, float* __restrict__ h1) {
  int tid = blockIdx.x * 256 + threadIdx.x;
  if (tid >= N_NODES * 128) return;
  int node = tid >> 7;
  int f = tid & 127;
  float4 a  = *(const float4*)(agg1 + node * 4);
  float4 xv = *(const float4*)(x + node * 4);
  float4 wr = *(const float4*)(W1_rel + f * 4);
  float4 wo = *(const float4*)(W1_root + f * 4);
  float v = b1[f]
      + a.x  * wr.x + a.y  * wr.y + a.z  * wr.z + a.w  * wr.w
      + xv.x * wo.x + xv.y * wo.y + xv.z * wo.z + xv.w * wo.w;
  h1[tid] = fmaxf(v, 0.0f);
}

// ============ layer 2: pull-aggregate h1 (F=128), one WAVE per node =========
// Per edge: 64 lanes read one 512B h1 row coalesced (float2/lane). Loop length
// is wave-uniform (one node per wave) -> no divergence. agg2 written once.
__global__ __launch_bounds__(256) void k_pull128(
    const float* __restrict__ h1, const int* __restrict__ row_start,
    const int* __restrict__ row_end, const int* __restrict__ csr_src,
    float* __restrict__ agg2) {
  int w = (blockIdx.x * 256 + threadIdx.x) >> 6;
  if (w >= N_NODES) return;
  int lane = threadIdx.x & 63;
  int rs = row_start[w], re = row_end[w];
  const float2* hb = (const float2*)h1 + lane;  // row stride 64 float2s
  float ax = 0.f, ay = 0.f;
  int i = rs;
  for (; i + 2 <= re; i += 2) {   // 2-way unroll: two loads in flight
    int s0 = csr_src[i];
    int s1 = csr_src[i + 1];
    float2 v0 = hb[(size_t)s0 * 64];
    float2 v1 = hb[(size_t)s1 * 64];
    ax += v0.x + v1.x;
    ay += v0.y + v1.y;
  }
  if (i < re) {
    int s0 = csr_src[i];
    float2 v0 = hb[(size_t)s0 * 64];
    ax += v0.x; ay += v0.y;
  }
  ((float2*)agg2)[(size_t)w * 64 + lane] = make_float2(ax, ay);
}

// ====== layer 2 dense + mean-pool partial: gsum[f] += relu(...) over nodes ==
__global__ __launch_bounds__(256) void k_layer2pool(
    const float* __restrict__ h1, const float* __restrict__ agg2,
    const float* __restrict__ W2_rel, const float* __restrict__ b2,
    const float* __restrict__ W2_root, float* __restrict__ gsum) {
  __shared__ float lds_w[256 * 32];   // [k][f_local], 32 KB
  int tid = threadIdx.x;
  int f0 = blockIdx.y * 32;

  {  // stage weights transposed: lds_w[k][fl] = Wcat[f0+fl][k]
    int fl = tid >> 3;
    int q  = tid & 7;
    int fg = f0 + fl;
    const float* wsrc = (q < 4) ? (W2_rel + fg * 128 + q * 32)
                                : (W2_root + fg * 128 + (q - 4) * 32);
    int kbase = q * 32;
#pragma unroll
    for (int j = 0; j < 32; j += 4) {
      float4 w = *(const float4*)(wsrc + j);
      lds_w[(kbase + j + 0) * 32 + fl] = w.x;
      lds_w[(kbase + j + 1) * 32 + fl] = w.y;
      lds_w[(kbase + j + 2) * 32 + fl] = w.z;
      lds_w[(kbase + j + 3) * 32 + fl] = w.w;
    }
  }
  __syncthreads();

  int f = tid & 31;
  int g = tid >> 5;
  float bias = b2[f0 + f];

  int npb = (N_NODES + gridDim.x - 1) / gridDim.x;
  int nstart = blockIdx.x * npb;
  int nend = min(nstart + npb, N_NODES);

  float fsum = 0.0f;
  for (int base = nstart + g * 4; base < nend; base += 32) {
    int m0 = base;
    int m1 = min(base + 1, N_NODES - 1);
    int m2 = min(base + 2, N_NODES - 1);
    int m3 = min(base + 3, N_NODES - 1);
    float acc0 = bias, acc1 = bias, acc2 = bias, acc3 = bias;

    const float* A0 = agg2 + (size_t)m0 * 128;
    const float* A1 = agg2 + (size_t)m1 * 128;
    const float* A2 = agg2 + (size_t)m2 * 128;
    const float* A3 = agg2 + (size_t)m3 * 128;
#pragma unroll 8
    for (int k = 0; k < 128; k += 4) {
      float4 x0 = *(const float4*)(A0 + k);
      float4 x1 = *(const float4*)(A1 + k);
      float4 x2 = *(const float4*)(A2 + k);
      float4 x3 = *(const float4*)(A3 + k);
      float w0 = lds_w[(k + 0) * 32 + f];
      float w1 = lds_w[(k + 1) * 32 + f];
      float w2 = lds_w[(k + 2) * 32 + f];
      float w3 = lds_w[(k + 3) * 32 + f];
      acc0 += x0.x * w0 + x0.y * w1 + x0.z * w2 + x0.w * w3;
      acc1 += x1.x * w0 + x1.y * w1 + x1.z * w2 + x1.w * w3;
      acc2 += x2.x * w0 + x2.y * w1 + x2.z * w2 + x2.w * w3;
      acc3 += x3.x * w0 + x3.y * w1 + x3.z * w2 + x3.w * w3;
    }
    const float* H0 = h1 + (size_t)m0 * 128;
    const float* H1 = h1 + (size_t)m1 * 128;
    const float* H2 = h1 + (size_t)m2 * 128;
    const float* H3 = h1 + (size_t)m3 * 128;
#pragma unroll 8
    for (int k = 0; k < 128; k += 4) {
      float4 x0 = *(const float4*)(H0 + k);
      float4 x1 = *(const float4*)(H1 + k);
      float4 x2 = *(const float4*)(H2 + k);
      float4 x3 = *(const float4*)(H3 + k);
      float w0 = lds_w[(128 + k + 0) * 32 + f];
      float w1 = lds_w[(128 + k + 1) * 32 + f];
      float w2 = lds_w[(128 + k + 2) * 32 + f];
      float w3 = lds_w[(128 + k + 3) * 32 + f];
      acc0 += x0.x * w0 + x0.y * w1 + x0.z * w2 + x0.w * w3;
      acc1 += x1.x * w0 + x1.y * w1 + x1.z * w2 + x1.w * w3;
      acc2 += x2.x * w0 + x2.y * w1 + x2.z * w2 + x2.w * w3;
      acc3 += x3.x * w0 + x3.y * w1 + x3.z * w2 + x3.w * w3;
    }
    fsum += (base + 0 < nend) ? fmaxf(acc0, 0.0f) : 0.0f;
    fsum += (base + 1 < nend) ? fmaxf(acc1, 0.0f) : 0.0f;
    fsum += (base + 2 < nend) ? fmaxf(acc2, 0.0f) : 0.0f;
    fsum += (base + 3 < nend) ? fmaxf(acc3, 0.0f) : 0.0f;
  }
  atomicAdd(gsum + f0 + f, fsum);
}

// ============ head: out = (gsum/N) @ Wlin.T + blin ============
__global__ void k_final(const float* __restrict__ gsum, const float* __restrict__ Wlin,
                        const float* __restrict__ blin, float* __restrict__ out) {
  int lane = threadIdx.x;  // 64 threads
  float g0 = gsum[lane];
  float g1 = gsum[lane + 64];
  float s0 = g0 * Wlin[lane]       + g1 * Wlin[lane + 64];
  float s1 = g0 * Wlin[128 + lane] + g1 * Wlin[192 + lane];
#pragma unroll
  for (int off = 32; off > 0; off >>= 1) {
    s0 += __shfl_down(s0, off);
    s1 += __shfl_down(s1, off);
  }
  if (lane == 0) {
    const float inv = 1.0f / (float)N_NODES;
    out[0] = s0 * inv + blin[0];
    out[1] = s1 * inv + blin[1];
  }
}

extern "C" void kernel_launch(void* const* d_in, const int* in_sizes, int n_in,
                              void* d_out, int out_size, void* d_ws, size_t ws_size,
                              hipStream_t stream) {
  const float* x       = (const float*)d_in[0];
  const int*   ei      = (const int*)d_in[1];
  const float* W1_rel  = (const float*)d_in[2];
  const float* b1      = (const float*)d_in[3];
  const float* W1_root = (const float*)d_in[4];
  const float* W2_rel  = (const float*)d_in[5];
  const float* b2      = (const float*)d_in[6];
  const float* W2_root = (const float*)d_in[7];
  const float* Wlin    = (const float*)d_in[8];
  const float* blin    = (const float*)d_in[9];
  const int* src = ei;            // edge_index[0]
  const int* dst = ei + N_EDGES;  // edge_index[1]
  float* out = (float*)d_out;

  // workspace layout (bytes):
  //   row_start @ 0        : 400,000
  //   cursor    @ 400,000  : 400,000   (histogram -> fill cursor -> row_end)
  //   gcursor   @ 800,000  : 128
  //   gsum      @ 800,128  : 512
  //   csr_src   @ 800,768  : 6,400,000  -> ends 7,200,768
  //   h1        @ 7,200,768: 51,200,000 -> ends 58,400,768
  //   agg2      @ 58,400,768: 51,200,000 -> ends 109,600,768
  //   agg1 overlays agg2 (only live before k_pull128 writes agg2)
  char* ws = (char*)d_ws;
  int*   row_start = (int*)(ws);
  int*   cursor    = (int*)(ws + 400000);
  int*   gcursor   = (int*)(ws + 800000);
  float* gsum      = (float*)(ws + 800128);
  int*   csr_src   = (int*)(ws + 800768);
  float* h1        = (float*)(ws + 7200768);
  float* agg2      = (float*)(ws + 58400768);
  float* agg1      = agg2;  // overlay: dead before agg2 is written

  hipMemsetAsync(cursor, 0, 400000, stream);
  hipMemsetAsync(gcursor, 0, 128, stream);
  hipMemsetAsync(gsum, 0, 512, stream);

  k_hist <<<(N_EDGES + 255) / 256, 256, 0, stream>>>(dst, cursor);
  k_alloc<<<(N_NODES + 255) / 256, 256, 0, stream>>>(cursor, row_start, gcursor);
  k_fill <<<(N_EDGES + 255) / 256, 256, 0, stream>>>(src, dst, cursor, csr_src);
  k_pull4<<<(N_NODES + 255) / 256, 256, 0, stream>>>(x, row_start, cursor, csr_src, agg1);
  k_layer1<<<(N_NODES * 128 + 255) / 256, 256, 0, stream>>>(x, agg1, W1_rel, b1, W1_root, h1);
  k_pull128<<<(N_NODES * 64 + 255) / 256, 256, 0, stream>>>(h1, row_start, cursor, csr_src, agg2);
  k_layer2pool<<<dim3(128, 4), 256, 0, stream>>>(h1, agg2, W2_rel, b2, W2_root, gsum);
  k_final<<<1, 64, 0, stream>>>(gsum, Wlin, blin, out);
}